// Round 1
// baseline (313.234 us; speedup 1.0000x reference)
//
#include <hip/hip_runtime.h>
#include <hip/hip_bf16.h>
#include <float.h>

#define NN 2048
#define HH 16
#define DDIM 64
#define QB 32
#define KB 64
#define SP 68   // ssh pitch in floats (padded to break bank alignment)

typedef __bf16 bf16x8 __attribute__((ext_vector_type(8)));
typedef __bf16 bf16x4 __attribute__((ext_vector_type(4)));
typedef float f32x4 __attribute__((ext_vector_type(4)));

// Flash-style fused attention with prev_attn + bias + bool-mask + causal.
// Grid: (32 pairs, 16 heads). Block: 256 threads = 4 waves.
// Block processes q-tile qt=p then qt=63-p (32 rows each) -> exactly 33 KV
// tiles of 64 per block (causal load balancing).
// Wave w: rows (w&1)*16..+16, kv-half (w>>1)*32..+32 of each 32x64 S tile.
__global__ __launch_bounds__(256, 2) void attend_fused(
    const float* __restrict__ qg, const float* __restrict__ kg,
    const float* __restrict__ vg, const unsigned int* __restrict__ maskw,
    const float* __restrict__ biasg, const float* __restrict__ prevg,
    float* __restrict__ outg)
{
  __shared__ char  ksh[KB * 128]   __attribute__((aligned(16))); // [kv][d] bf16, swizzled
  __shared__ char  vsh[DDIM * 128] __attribute__((aligned(16))); // [d][kv] bf16, swizzled
  __shared__ float ssh[QB * SP]    __attribute__((aligned(16))); // padded f32 S tile
  __shared__ char  psh[QB * 128]   __attribute__((aligned(16))); // [r][kv] bf16, swizzled
  __shared__ float scale_s[QB];
  __shared__ float m_s[QB], l_s[QB];
  __shared__ float vmean_s[DDIM];

  const int t    = threadIdx.x;
  const int lane = t & 63;
  const int w    = t >> 6;
  const int pidx = blockIdx.x;
  const int h    = blockIdx.y;

  // --- mask element-width detection: 4-byte (int32/float32 bool) vs 1-byte ---
  unsigned int mwrd = maskw[t & 255];
  const int mask4 = __syncthreads_and(mwrd == 0u || mwrd == 1u || mwrd == 0x3F800000u);

  const int r0  = (w & 1) * 16;   // wave's row strip inside 32-row q-tile
  const int c0  = (w >> 1) * 32;  // wave's kv half inside 64-col tile
  const int lhi = lane >> 4;
  const int llo = lane & 15;
  const int sr  = t >> 3;         // softmax-phase row 0..31
  const int sc  = (t & 7) * 8;    // softmax-phase col base

  for (int sub = 0; sub < 2; ++sub) {
    const int qt    = sub ? (63 - pidx) : pidx;
    const int qrow0 = qt * QB;

    // --- Q fragments, scale (1/8, exact) folded in ---
    bf16x8 aq[2];
    {
      const int row = qrow0 + r0 + llo;
      const float* qp = qg + ((size_t)(h * NN + row)) * DDIM + lhi * 8;
#pragma unroll
      for (int ks = 0; ks < 2; ++ks) {
        float4 f0 = *(const float4*)(qp + ks * 32);
        float4 f1 = *(const float4*)(qp + ks * 32 + 4);
        bf16x8 a;
        a[0] = (__bf16)(f0.x * 0.125f); a[1] = (__bf16)(f0.y * 0.125f);
        a[2] = (__bf16)(f0.z * 0.125f); a[3] = (__bf16)(f0.w * 0.125f);
        a[4] = (__bf16)(f1.x * 0.125f); a[5] = (__bf16)(f1.y * 0.125f);
        a[6] = (__bf16)(f1.z * 0.125f); a[7] = (__bf16)(f1.w * 0.125f);
        aq[ks] = a;
      }
    }

    f32x4 oacc[4];
#pragma unroll
    for (int i = 0; i < 4; ++i) { f32x4 z = {0.f, 0.f, 0.f, 0.f}; oacc[i] = z; }
    float m_r = -FLT_MAX, l_r = 0.f;
    const int irow = qrow0 + sr;

    const int Tq = (qrow0 + QB - 1) / KB + 1;
    for (int tt = 0; tt < Tq; ++tt) {
      const int kv0 = tt * KB;
      // ---- stage K (row-major) and V (transposed), f32->bf16, swizzled ----
#pragma unroll
      for (int e = 0; e < 4; ++e) {
        const int f4  = t + e * 256;       // 0..1023 float4s
        const int row = f4 >> 4;           // kv index in tile
        const int cb  = (f4 & 15) * 4;     // d base
        const size_t gofs = ((size_t)(h * NN + kv0 + row)) * DDIM + cb;
        float4 kf = *(const float4*)(kg + gofs);
        bf16x4 kb4;
        kb4[0] = (__bf16)kf.x; kb4[1] = (__bf16)kf.y;
        kb4[2] = (__bf16)kf.z; kb4[3] = (__bf16)kf.w;
        *(bf16x4*)(ksh + (((row << 7) + (cb << 1)) ^ ((row & 7) << 4))) = kb4;
        float4 vf = *(const float4*)(vg + gofs);
        *(__bf16*)(vsh + ((((cb + 0) << 7) + (row << 1)) ^ (((cb + 0) & 7) << 4))) = (__bf16)vf.x;
        *(__bf16*)(vsh + ((((cb + 1) << 7) + (row << 1)) ^ (((cb + 1) & 7) << 4))) = (__bf16)vf.y;
        *(__bf16*)(vsh + ((((cb + 2) << 7) + (row << 1)) ^ (((cb + 2) & 7) << 4))) = (__bf16)vf.z;
        *(__bf16*)(vsh + ((((cb + 3) << 7) + (row << 1)) ^ (((cb + 3) & 7) << 4))) = (__bf16)vf.w;
      }
      __syncthreads();
      // ---- QK^T (wave: 16 rows x 32 cols) ----
#pragma unroll
      for (int cf = 0; cf < 2; ++cf) {
        f32x4 sacc = {0.f, 0.f, 0.f, 0.f};
        const int jcol = c0 + cf * 16 + llo;
#pragma unroll
        for (int ks = 0; ks < 2; ++ks) {
          const int d0 = ks * 32 + lhi * 8;
          bf16x8 bk = *(const bf16x8*)(ksh + (((jcol << 7) + (d0 << 1)) ^ ((jcol & 7) << 4)));
          sacc = __builtin_amdgcn_mfma_f32_16x16x32_bf16(aq[ks], bk, sacc, 0, 0, 0);
        }
        const int srow = r0 + lhi * 4;  // C layout: col=lane&15, row=(lane>>4)*4+reg
        ssh[(srow + 0) * SP + jcol] = sacc[0];
        ssh[(srow + 1) * SP + jcol] = sacc[1];
        ssh[(srow + 2) * SP + jcol] = sacc[2];
        ssh[(srow + 3) * SP + jcol] = sacc[3];
      }
      __syncthreads();
      // ---- softmax: thread t owns row sr, cols sc..sc+7; streams prev+bias ----
      {
        const size_t base = ((size_t)(h * NN) + irow) * NN + kv0 + sc;
        float4 pv0 = *(const float4*)(prevg + base);
        float4 pv1 = *(const float4*)(prevg + base + 4);
        float4 bb0 = *(const float4*)(biasg + base);
        float4 bb1 = *(const float4*)(biasg + base + 4);
        unsigned int mb[8];
        const size_t midx = (size_t)irow * NN + kv0 + sc;
        if (mask4) {
          const unsigned int* mp = maskw + midx;
          mb[0] = mp[0]; mb[1] = mp[1]; mb[2] = mp[2]; mb[3] = mp[3];
          mb[4] = mp[4]; mb[5] = mp[5]; mb[6] = mp[6]; mb[7] = mp[7];
        } else {
          const unsigned char* mc = (const unsigned char*)maskw + midx;
          unsigned int w0 = *(const unsigned int*)(mc);
          unsigned int w1 = *(const unsigned int*)(mc + 4);
          mb[0] = w0 & 0xffu; mb[1] = (w0 >> 8) & 0xffu;
          mb[2] = (w0 >> 16) & 0xffu; mb[3] = w0 >> 24;
          mb[4] = w1 & 0xffu; mb[5] = (w1 >> 8) & 0xffu;
          mb[6] = (w1 >> 16) & 0xffu; mb[7] = w1 >> 24;
        }
        float pa[8] = {pv0.x, pv0.y, pv0.z, pv0.w, pv1.x, pv1.y, pv1.z, pv1.w};
        float ba[8] = {bb0.x, bb0.y, bb0.z, bb0.w, bb1.x, bb1.y, bb1.z, bb1.w};
        float sv[8];
        float pmax = -FLT_MAX;
#pragma unroll
        for (int jj = 0; jj < 8; ++jj) {
          const int j = kv0 + sc + jj;
          float s = ssh[sr * SP + sc + jj] + pa[jj] + ba[jj];
          if (j > irow || mb[jj] == 0u) s = -FLT_MAX;
          sv[jj] = s;
          pmax = fmaxf(pmax, s);
        }
        pmax = fmaxf(pmax, __shfl_xor(pmax, 1));
        pmax = fmaxf(pmax, __shfl_xor(pmax, 2));
        pmax = fmaxf(pmax, __shfl_xor(pmax, 4));
        const float mnew = fmaxf(m_r, pmax);
        const float resc = __expf(m_r - mnew);  // exp(0)=1 when both -FLT_MAX
        float psum = 0.f;
        bf16x8 pb;
#pragma unroll
        for (int jj = 0; jj < 8; ++jj) {
          float p = __expf(sv[jj] - mnew);
          psum += p;
          pb[jj] = (__bf16)p;
        }
        *(bf16x8*)(psh + (((sr << 7) + (sc << 1)) ^ ((sr & 7) << 4))) = pb;
        psum += __shfl_xor(psum, 1);
        psum += __shfl_xor(psum, 2);
        psum += __shfl_xor(psum, 4);
        l_r = l_r * resc + psum;
        m_r = mnew;
        if ((t & 7) == 0) scale_s[sr] = resc;
      }
      __syncthreads();
      // ---- rescale O and PV (wave's kv half: one K=32 step) ----
      {
        const int rbase = r0 + lhi * 4;
        const float f0s = scale_s[rbase + 0], f1s = scale_s[rbase + 1];
        const float f2s = scale_s[rbase + 2], f3s = scale_s[rbase + 3];
        const int prow = r0 + llo;
        const int pk   = c0 + lhi * 8;
        bf16x8 pfrag = *(const bf16x8*)(psh + (((prow << 7) + (pk << 1)) ^ ((prow & 7) << 4)));
#pragma unroll
        for (int df = 0; df < 4; ++df) {
          f32x4 oc = oacc[df];
          oc[0] *= f0s; oc[1] *= f1s; oc[2] *= f2s; oc[3] *= f3s;
          const int drow = df * 16 + llo;
          bf16x8 vfrag = *(const bf16x8*)(vsh + (((drow << 7) + (pk << 1)) ^ ((drow & 7) << 4)));
          oacc[df] = __builtin_amdgcn_mfma_f32_16x16x32_bf16(pfrag, vfrag, oc, 0, 0, 0);
        }
      }
      __syncthreads();
    } // kv tiles

    // ---- epilogue ----
    if ((t & 7) == 0) { m_s[sr] = m_r; l_s[sr] = l_r; }
    const int anyNeed = __syncthreads_or(((t & 7) == 0) && (m_r == -FLT_MAX));
    if (anyNeed) {
      // fully-masked row(s): ref softmax is uniform over ALL 2048 -> col-mean of V
      if (t < DDIM) vmean_s[t] = 0.f;
      __syncthreads();
      {
        const int d = t & 63, part = t >> 6;
        float s = 0.f;
        for (int j = part; j < NN; j += 4) s += vg[((size_t)(h * NN + j)) * DDIM + d];
        atomicAdd(&vmean_s[d], s);
      }
      __syncthreads();
      if (t < DDIM) vmean_s[t] *= (1.0f / (float)NN);
      __syncthreads();
    }
    // combine the two kv-half partial accumulators via ssh
    if (w >= 2) {
      const int rbase = r0 + lhi * 4;
#pragma unroll
      for (int df = 0; df < 4; ++df) {
        const int d = df * 16 + llo;
        ssh[(rbase + 0) * SP + d] = oacc[df][0];
        ssh[(rbase + 1) * SP + d] = oacc[df][1];
        ssh[(rbase + 2) * SP + d] = oacc[df][2];
        ssh[(rbase + 3) * SP + d] = oacc[df][3];
      }
    }
    __syncthreads();
    if (w < 2) {
      const int rbase = r0 + lhi * 4;
#pragma unroll
      for (int df = 0; df < 4; ++df) {
        const int d = df * 16 + llo;
#pragma unroll
        for (int rr = 0; rr < 4; ++rr) {
          const int row = rbase + rr;
          const float val = oacc[df][rr] + ssh[row * SP + d];
          const float mm  = m_s[row];
          const float res = (mm == -FLT_MAX) ? vmean_s[d] : val / l_s[row];
          outg[((size_t)(h * NN) + qrow0 + row) * DDIM + d] = res;
        }
      }
    }
    __syncthreads();
  } // sub (two paired q-tiles)
}

extern "C" void kernel_launch(void* const* d_in, const int* in_sizes, int n_in,
                              void* d_out, int out_size, void* d_ws, size_t ws_size,
                              hipStream_t stream) {
  (void)in_sizes; (void)n_in; (void)d_ws; (void)ws_size; (void)out_size;
  const float* q    = (const float*)d_in[0];
  const float* k    = (const float*)d_in[1];
  const float* v    = (const float*)d_in[2];
  const unsigned int* mask = (const unsigned int*)d_in[3];
  const float* bias = (const float*)d_in[4];
  const float* prev = (const float*)d_in[5];
  float* out = (float*)d_out;

  dim3 grid(32, HH);
  attend_fused<<<grid, 256, 0, stream>>>(q, k, v, mask, bias, prev, out);
}

// Round 2
// 244.867 us; speedup vs baseline: 1.2792x; 1.2792x over previous
//
#include <hip/hip_runtime.h>
#include <hip/hip_bf16.h>
#include <float.h>

#define NN 2048
#define HH 16
#define DDIM 64
#define QB 32
#define KB 64
#define SP 68   // ssh pitch in floats (padded to break bank alignment)

typedef __bf16 bf16x8 __attribute__((ext_vector_type(8)));
typedef __bf16 bf16x4 __attribute__((ext_vector_type(4)));
typedef float f32x4 __attribute__((ext_vector_type(4)));

// Raw barrier: LDS-writes visible, but outstanding GLOBAL loads (prefetch)
// are NOT drained (unlike __syncthreads' vmcnt(0) drain).
__device__ __forceinline__ void barw() {
  __builtin_amdgcn_sched_barrier(0);
  asm volatile("s_waitcnt lgkmcnt(0)" ::: "memory");
  __builtin_amdgcn_s_barrier();
  __builtin_amdgcn_sched_barrier(0);
}

// Flash-style fused attention with prev_attn + bias + bool-mask + causal.
// Grid: (32 pairs, 16 heads). Block: 256 threads = 4 waves.
// Block processes q-tile qt=p then qt=63-p (32 rows each) -> exactly 33 KV
// tiles of 64 per block (causal load balancing).
// Wave w: rows (w&1)*16..+16, kv-half (w>>1)*32..+32 of each 32x64 S tile.
// R2: register prefetch of next tile's K/V/prev/bias/mask across raw barriers.
__global__ __launch_bounds__(256, 2) void attend_fused(
    const float* __restrict__ qg, const float* __restrict__ kg,
    const float* __restrict__ vg, const unsigned int* __restrict__ maskw,
    const float* __restrict__ biasg, const float* __restrict__ prevg,
    float* __restrict__ outg)
{
  __shared__ char  ksh[KB * 128]   __attribute__((aligned(16))); // [kv][d] bf16, swizzled
  __shared__ char  vsh[DDIM * 128] __attribute__((aligned(16))); // [d][kv] bf16, swizzled
  __shared__ float ssh[QB * SP]    __attribute__((aligned(16))); // padded f32 S tile
  __shared__ char  psh[QB * 128]   __attribute__((aligned(16))); // [r][kv] bf16, swizzled
  __shared__ float scale_s[QB];
  __shared__ float m_s[QB], l_s[QB];
  __shared__ float vmean_s[DDIM];

  const int t    = threadIdx.x;
  const int lane = t & 63;
  const int w    = t >> 6;
  const int pidx = blockIdx.x;
  const int h    = blockIdx.y;

  // --- mask element-width detection: 4-byte (int32/float32 bool) vs 1-byte ---
  unsigned int mwrd = maskw[t & 255];
  const int mask4 = __syncthreads_and(mwrd == 0u || mwrd == 1u || mwrd == 0x3F800000u);

  const int r0  = (w & 1) * 16;   // wave's row strip inside 32-row q-tile
  const int c0  = (w >> 1) * 32;  // wave's kv half inside 64-col tile
  const int lhi = lane >> 4;
  const int llo = lane & 15;
  const int sr  = t >> 3;         // softmax-phase row 0..31
  const int sc  = (t & 7) * 8;    // softmax-phase col base

  for (int sub = 0; sub < 2; ++sub) {
    const int qt    = sub ? (63 - pidx) : pidx;
    const int qrow0 = qt * QB;

    // --- Q fragments, scale (1/8, exact) folded in ---
    bf16x8 aq[2];
    {
      const int row = qrow0 + r0 + llo;
      const float* qp = qg + ((size_t)(h * NN + row)) * DDIM + lhi * 8;
#pragma unroll
      for (int ks = 0; ks < 2; ++ks) {
        float4 f0 = *(const float4*)(qp + ks * 32);
        float4 f1 = *(const float4*)(qp + ks * 32 + 4);
        bf16x8 a;
        a[0] = (__bf16)(f0.x * 0.125f); a[1] = (__bf16)(f0.y * 0.125f);
        a[2] = (__bf16)(f0.z * 0.125f); a[3] = (__bf16)(f0.w * 0.125f);
        a[4] = (__bf16)(f1.x * 0.125f); a[5] = (__bf16)(f1.y * 0.125f);
        a[6] = (__bf16)(f1.z * 0.125f); a[7] = (__bf16)(f1.w * 0.125f);
        aq[ks] = a;
      }
    }

    f32x4 oacc[4];
#pragma unroll
    for (int i = 0; i < 4; ++i) { f32x4 z = {0.f, 0.f, 0.f, 0.f}; oacc[i] = z; }
    float m_r = -FLT_MAX, l_r = 0.f;
    const int irow = qrow0 + sr;

    // ---- prefetch registers ----
    float4 kpre[4], vpre[4];
    float4 ppre0, ppre1, bpre0, bpre1;
    uint4  mq0, mq1;

    auto issueKV = [&](int kv0) {
#pragma unroll
      for (int e = 0; e < 4; ++e) {
        const int f4  = t + e * 256;
        const int row = f4 >> 4;
        const int cb  = (f4 & 15) * 4;
        const size_t gofs = ((size_t)(h * NN + kv0 + row)) * DDIM + cb;
        kpre[e] = *(const float4*)(kg + gofs);
        vpre[e] = *(const float4*)(vg + gofs);
      }
    };
    auto issuePB = [&](int kv0) {
      const size_t base = ((size_t)(h * NN) + irow) * NN + kv0 + sc;
      ppre0 = *(const float4*)(prevg + base);
      ppre1 = *(const float4*)(prevg + base + 4);
      bpre0 = *(const float4*)(biasg + base);
      bpre1 = *(const float4*)(biasg + base + 4);
      const size_t midx = (size_t)irow * NN + kv0 + sc;
      if (mask4) {
        mq0 = *(const uint4*)(maskw + midx);
        mq1 = *(const uint4*)(maskw + midx + 4);
      } else {
        const unsigned int* mp = (const unsigned int*)((const unsigned char*)maskw + midx);
        mq0.x = mp[0]; mq0.y = mp[1];
      }
    };

    const int Tq = (qrow0 + QB - 1) / KB + 1;
    issueKV(0);
    issuePB(0);

    for (int tt = 0; tt < Tq; ++tt) {
      const int kv0 = tt * KB;
      // ---- phase 1: stage K (row-major) and V (transposed) from prefetch regs ----
#pragma unroll
      for (int e = 0; e < 4; ++e) {
        const int f4  = t + e * 256;       // 0..1023 float4s
        const int row = f4 >> 4;           // kv index in tile
        const int cb  = (f4 & 15) * 4;     // d base
        float4 kf = kpre[e];
        bf16x4 kb4;
        kb4[0] = (__bf16)kf.x; kb4[1] = (__bf16)kf.y;
        kb4[2] = (__bf16)kf.z; kb4[3] = (__bf16)kf.w;
        *(bf16x4*)(ksh + (((row << 7) + (cb << 1)) ^ ((row & 7) << 4))) = kb4;
        float4 vf = vpre[e];
        *(__bf16*)(vsh + ((((cb + 0) << 7) + (row << 1)) ^ (((cb + 0) & 7) << 4))) = (__bf16)vf.x;
        *(__bf16*)(vsh + ((((cb + 1) << 7) + (row << 1)) ^ (((cb + 1) & 7) << 4))) = (__bf16)vf.y;
        *(__bf16*)(vsh + ((((cb + 2) << 7) + (row << 1)) ^ (((cb + 2) & 7) << 4))) = (__bf16)vf.z;
        *(__bf16*)(vsh + ((((cb + 3) << 7) + (row << 1)) ^ (((cb + 3) & 7) << 4))) = (__bf16)vf.w;
      }
      // keep current tile's softmax operands
      const float4 pc0 = ppre0, pc1 = ppre1, bc0 = bpre0, bc1 = bpre1;
      const uint4  mc0 = mq0,  mc1 = mq1;
      // ---- issue next tile's loads (stay in flight across raw barriers) ----
      if (tt + 1 < Tq) { issueKV(kv0 + KB); issuePB(kv0 + KB); }
      barw();
      // ---- phase 2: QK^T (wave: 16 rows x 32 cols) ----
#pragma unroll
      for (int cf = 0; cf < 2; ++cf) {
        f32x4 sacc = {0.f, 0.f, 0.f, 0.f};
        const int jcol = c0 + cf * 16 + llo;
#pragma unroll
        for (int ks = 0; ks < 2; ++ks) {
          const int d0 = ks * 32 + lhi * 8;
          bf16x8 bk = *(const bf16x8*)(ksh + (((jcol << 7) + (d0 << 1)) ^ ((jcol & 7) << 4)));
          sacc = __builtin_amdgcn_mfma_f32_16x16x32_bf16(aq[ks], bk, sacc, 0, 0, 0);
        }
        const int srow = r0 + lhi * 4;  // C layout: col=lane&15, row=(lane>>4)*4+reg
        ssh[(srow + 0) * SP + jcol] = sacc[0];
        ssh[(srow + 1) * SP + jcol] = sacc[1];
        ssh[(srow + 2) * SP + jcol] = sacc[2];
        ssh[(srow + 3) * SP + jcol] = sacc[3];
      }
      barw();
      // ---- phase 3: softmax: thread t owns row sr, cols sc..sc+7 ----
      {
        unsigned int mb[8];
        if (mask4) {
          mb[0] = mc0.x; mb[1] = mc0.y; mb[2] = mc0.z; mb[3] = mc0.w;
          mb[4] = mc1.x; mb[5] = mc1.y; mb[6] = mc1.z; mb[7] = mc1.w;
        } else {
          const unsigned int w0 = mc0.x, w1 = mc0.y;
          mb[0] = w0 & 0xffu; mb[1] = (w0 >> 8) & 0xffu;
          mb[2] = (w0 >> 16) & 0xffu; mb[3] = w0 >> 24;
          mb[4] = w1 & 0xffu; mb[5] = (w1 >> 8) & 0xffu;
          mb[6] = (w1 >> 16) & 0xffu; mb[7] = w1 >> 24;
        }
        float pa[8] = {pc0.x, pc0.y, pc0.z, pc0.w, pc1.x, pc1.y, pc1.z, pc1.w};
        float ba[8] = {bc0.x, bc0.y, bc0.z, bc0.w, bc1.x, bc1.y, bc1.z, bc1.w};
        float sv[8];
        float pmax = -FLT_MAX;
#pragma unroll
        for (int jj = 0; jj < 8; ++jj) {
          const int j = kv0 + sc + jj;
          float s = ssh[sr * SP + sc + jj] + pa[jj] + ba[jj];
          if (j > irow || mb[jj] == 0u) s = -FLT_MAX;
          sv[jj] = s;
          pmax = fmaxf(pmax, s);
        }
        pmax = fmaxf(pmax, __shfl_xor(pmax, 1));
        pmax = fmaxf(pmax, __shfl_xor(pmax, 2));
        pmax = fmaxf(pmax, __shfl_xor(pmax, 4));
        const float mnew = fmaxf(m_r, pmax);
        const float resc = __expf(m_r - mnew);  // exp(0)=1 when both -FLT_MAX
        float psum = 0.f;
        bf16x8 pb;
#pragma unroll
        for (int jj = 0; jj < 8; ++jj) {
          float p = __expf(sv[jj] - mnew);
          psum += p;
          pb[jj] = (__bf16)p;
        }
        *(bf16x8*)(psh + (((sr << 7) + (sc << 1)) ^ ((sr & 7) << 4))) = pb;
        psum += __shfl_xor(psum, 1);
        psum += __shfl_xor(psum, 2);
        psum += __shfl_xor(psum, 4);
        l_r = l_r * resc + psum;
        m_r = mnew;
        if ((t & 7) == 0) scale_s[sr] = resc;
      }
      barw();
      // ---- phase 4: rescale O and PV (wave's kv half: one K=32 step) ----
      {
        const int rbase = r0 + lhi * 4;
        const float f0s = scale_s[rbase + 0], f1s = scale_s[rbase + 1];
        const float f2s = scale_s[rbase + 2], f3s = scale_s[rbase + 3];
        const int prow = r0 + llo;
        const int pk   = c0 + lhi * 8;
        bf16x8 pfrag = *(const bf16x8*)(psh + (((prow << 7) + (pk << 1)) ^ ((prow & 7) << 4)));
#pragma unroll
        for (int df = 0; df < 4; ++df) {
          f32x4 oc = oacc[df];
          oc[0] *= f0s; oc[1] *= f1s; oc[2] *= f2s; oc[3] *= f3s;
          const int drow = df * 16 + llo;
          bf16x8 vfrag = *(const bf16x8*)(vsh + (((drow << 7) + (pk << 1)) ^ ((drow & 7) << 4)));
          oacc[df] = __builtin_amdgcn_mfma_f32_16x16x32_bf16(pfrag, vfrag, oc, 0, 0, 0);
        }
      }
      barw();
    } // kv tiles

    // ---- epilogue (no prefetch outstanding; full __syncthreads fine) ----
    if ((t & 7) == 0) { m_s[sr] = m_r; l_s[sr] = l_r; }
    const int anyNeed = __syncthreads_or(((t & 7) == 0) && (m_r == -FLT_MAX));
    if (anyNeed) {
      // fully-masked row(s): ref softmax is uniform over ALL 2048 -> col-mean of V
      if (t < DDIM) vmean_s[t] = 0.f;
      __syncthreads();
      {
        const int d = t & 63, part = t >> 6;
        float s = 0.f;
        for (int j = part; j < NN; j += 4) s += vg[((size_t)(h * NN + j)) * DDIM + d];
        atomicAdd(&vmean_s[d], s);
      }
      __syncthreads();
      if (t < DDIM) vmean_s[t] *= (1.0f / (float)NN);
      __syncthreads();
    }
    // combine the two kv-half partial accumulators via ssh
    if (w >= 2) {
      const int rbase = r0 + lhi * 4;
#pragma unroll
      for (int df = 0; df < 4; ++df) {
        const int d = df * 16 + llo;
        ssh[(rbase + 0) * SP + d] = oacc[df][0];
        ssh[(rbase + 1) * SP + d] = oacc[df][1];
        ssh[(rbase + 2) * SP + d] = oacc[df][2];
        ssh[(rbase + 3) * SP + d] = oacc[df][3];
      }
    }
    __syncthreads();
    if (w < 2) {
      const int rbase = r0 + lhi * 4;
#pragma unroll
      for (int df = 0; df < 4; ++df) {
        const int d = df * 16 + llo;
#pragma unroll
        for (int rr = 0; rr < 4; ++rr) {
          const int row = rbase + rr;
          const float val = oacc[df][rr] + ssh[row * SP + d];
          const float mm  = m_s[row];
          const float res = (mm == -FLT_MAX) ? vmean_s[d] : val / l_s[row];
          outg[((size_t)(h * NN) + qrow0 + row) * DDIM + d] = res;
        }
      }
    }
    __syncthreads();
  } // sub (two paired q-tiles)
}

extern "C" void kernel_launch(void* const* d_in, const int* in_sizes, int n_in,
                              void* d_out, int out_size, void* d_ws, size_t ws_size,
                              hipStream_t stream) {
  (void)in_sizes; (void)n_in; (void)d_ws; (void)ws_size; (void)out_size;
  const float* q    = (const float*)d_in[0];
  const float* k    = (const float*)d_in[1];
  const float* v    = (const float*)d_in[2];
  const unsigned int* mask = (const unsigned int*)d_in[3];
  const float* bias = (const float*)d_in[4];
  const float* prev = (const float*)d_in[5];
  float* out = (float*)d_out;

  dim3 grid(32, HH);
  attend_fused<<<grid, 256, 0, stream>>>(q, k, v, mask, bias, prev, out);
}